// Round 3
// baseline (130.828 us; speedup 1.0000x reference)
//
#include <hip/hip_runtime.h>

#define N_NODES 50000
#define N_EDGES 800000
#define D 128
#define LDA 136   // padded LDS row stride in shorts (+4 banks/row -> 2-way alias, free)

#define SEARCH_BLOCKS 196   // ceil(50001/256)
#define GEMM_BLOCKS   391   // ceil(50000/128)

typedef __attribute__((ext_vector_type(8))) short bf16x8;
typedef __attribute__((ext_vector_type(4))) float f32x4;

__device__ __forceinline__ unsigned short f2bf(float f) {
    union { float f; unsigned u; } v; v.f = f;
    return (unsigned short)((v.u + 0x7fffu + ((v.u >> 16) & 1u)) >> 16);
}
__device__ __forceinline__ float bflo(unsigned u) {
    union { unsigned u; float f; } c; c.u = u << 16; return c.f;
}
__device__ __forceinline__ float bfhi(unsigned u) {
    union { unsigned u; float f; } c; c.u = u & 0xffff0000u; return c.f;
}

// ------- KH: fused row_ptr searches + (h = bf16(X)@bf16(W) MFMA, a_src/a_dst) ----
// R0-verified structure. X staged via nontemporal f32x4 loads (read-once stream).
__global__ __launch_bounds__(256) void kh_fused(const float* __restrict__ X,
                                                const int* __restrict__ edges,
                                                const float* __restrict__ W,
                                                const float* __restrict__ ka,
                                                unsigned short* __restrict__ h,
                                                float* __restrict__ a_src,
                                                float* __restrict__ a_dst,
                                                int* __restrict__ row_ptr) {
    __shared__ unsigned short As[128 * LDA];   // [m][k], 34.8 KB
    __shared__ unsigned short Bs[128 * LDA];   // [n][k], 34.8 KB
    __shared__ float kas[2 * D];               // 1 KB
    int b = blockIdx.x, tid = threadIdx.x;

    if (b < SEARCH_BLOCKS) {                   // row_ptr[n] = lower_bound(src, n)
        int n = b * 256 + tid;
        if (n > N_NODES) return;
        int lo = 0, hi = N_EDGES;
        while (lo < hi) {
            int mid = (lo + hi) >> 1;
            if (edges[2 * mid] < n) lo = mid + 1; else hi = mid;
        }
        row_ptr[n] = lo;
        return;
    }

    int row0 = (b - SEARCH_BLOCKS) * 128;
    kas[tid] = ka[tid];
    // Bs <- bf16(W^T): thread reads W[k][n4..n4+3] coalesced, scatters 4 u16.
    for (int i = tid; i < 128 * 32; i += 256) {
        int k = i >> 5, n4 = (i & 31) * 4;
        float4 w = *(const float4*)(W + k * D + n4);
        Bs[(n4 + 0) * LDA + k] = f2bf(w.x);
        Bs[(n4 + 1) * LDA + k] = f2bf(w.y);
        Bs[(n4 + 2) * LDA + k] = f2bf(w.z);
        Bs[(n4 + 3) * LDA + k] = f2bf(w.w);
    }
    // As <- bf16(X tile): nontemporal 16B loads, read-once stream
    for (int i = tid; i < 2048; i += 256) {
        int r = i >> 4, c = i & 15;
        int gr = row0 + r;
        union { unsigned short us[8]; uint4 q; } pk;
        if (gr < N_NODES) {
            const float* xp = X + (size_t)gr * D + c * 8;
            f32x4 u = __builtin_nontemporal_load((const f32x4*)xp);
            f32x4 v = __builtin_nontemporal_load((const f32x4*)(xp + 4));
#pragma unroll
            for (int j = 0; j < 4; ++j) { pk.us[j] = f2bf(u[j]); pk.us[4 + j] = f2bf(v[j]); }
        } else pk.q = make_uint4(0u, 0u, 0u, 0u);
        *(uint4*)&As[r * LDA + c * 8] = pk.q;
    }
    __syncthreads();

    int wave = tid >> 6, lane = tid & 63;
    int m16 = lane & 15, quad = lane >> 4;
    int wr0 = wave * 32;                       // 2 row-tiles per wave
    f32x4 acc[2][8];
#pragma unroll
    for (int i = 0; i < 2; ++i)
#pragma unroll
        for (int j = 0; j < 8; ++j) acc[i][j] = (f32x4){0.f, 0.f, 0.f, 0.f};

    for (int k0 = 0; k0 < D; k0 += 32) {
        bf16x8 a0 = *(const bf16x8*)&As[(wr0 + m16) * LDA + k0 + quad * 8];
        bf16x8 a1 = *(const bf16x8*)&As[(wr0 + 16 + m16) * LDA + k0 + quad * 8];
#pragma unroll
        for (int j = 0; j < 8; ++j) {
            bf16x8 bf = *(const bf16x8*)&Bs[(j * 16 + m16) * LDA + k0 + quad * 8];
            acc[0][j] = __builtin_amdgcn_mfma_f32_16x16x32_bf16(a0, bf, acc[0][j], 0, 0, 0);
            acc[1][j] = __builtin_amdgcn_mfma_f32_16x16x32_bf16(a1, bf, acc[1][j], 0, 0, 0);
        }
    }

    // h store: C/D layout col=lane&15, row=quad*4+reg (m89-verified)
#pragma unroll
    for (int i = 0; i < 2; ++i)
#pragma unroll
        for (int j = 0; j < 8; ++j)
#pragma unroll
            for (int r = 0; r < 4; ++r) {
                int row = row0 + wr0 + i * 16 + quad * 4 + r;
                if (row < N_NODES)
                    h[(size_t)row * D + j * 16 + m16] = f2bf(acc[i][j][r]);
            }

    // a_src/a_dst from fp32 accumulators: a_src[row] = sum_col h[row][col]*ka[col]
#pragma unroll
    for (int i = 0; i < 2; ++i)
#pragma unroll
        for (int r = 0; r < 4; ++r) {
            float ps = 0.f, pd = 0.f;
#pragma unroll
            for (int j = 0; j < 8; ++j) {
                float val = acc[i][j][r];
                ps += val * kas[j * 16 + m16];
                pd += val * kas[D + j * 16 + m16];
            }
            for (int off = 8; off > 0; off >>= 1) {
                ps += __shfl_down(ps, off, 16);
                pd += __shfl_down(pd, off, 16);
            }
            int row = row0 + wr0 + i * 16 + quad * 4 + r;
            if (m16 == 0 && row < N_NODES) { a_src[row] = ps; a_dst[row] = pd; }
        }
}

// ---------------- K3: wave-per-node gather, 4 loads in flight (R0 structure) -----
// Scores fused in-loop: a_dst gather + expf chain is independent of the h gathers,
// so the compiler overlaps them. int2 edge load = one coalesced 8B instruction.
__global__ __launch_bounds__(256) void k3(const int* __restrict__ edges,
                                          const int* __restrict__ row_ptr,
                                          const unsigned short* __restrict__ h,
                                          const float* __restrict__ a_src,
                                          const float* __restrict__ a_dst,
                                          float* __restrict__ out) {
    int node = blockIdx.x * 4 + (threadIdx.x >> 6);
    if (node >= N_NODES) return;
    int lane = threadIdx.x & 63;
    int q = lane >> 4;          // quarter-wave 0..3
    int l16 = lane & 15;        // 16 lanes x 8 cols cover a 128-col row

    int start = row_ptr[node], end = row_ptr[node + 1];
    float asn = a_src[node];
    const unsigned short* hl = h + (l16 << 3);

    float4 accA = make_float4(0.f, 0.f, 0.f, 0.f);
    float4 accB = make_float4(0.f, 0.f, 0.f, 0.f);
    float dn = 0.f;

    for (int base = start; base < end; base += 64) {
        int cnt = min(64, end - base);
        int d = 0; float s = 0.f;
        if (lane < cnt) {
            int2 sd = ((const int2*)edges)[base + lane];
            d = sd.y;
            float lg = asn + a_dst[d];
            lg = (lg >= 0.f) ? lg : 0.2f * lg;      // leaky_relu 0.2
            lg = fminf(fmaxf(lg, -2.f), 2.f);       // clip
            s = __expf(lg);
        }
        for (int j = 0; j < cnt; j += 16) {         // 16 edges/iter, 4 loads/lane in flight
            float sj[4]; int dj[4];
#pragma unroll
            for (int t = 0; t < 4; ++t) {
                sj[t] = __shfl(s, j + q + 4 * t, 64);   // 0 for dead slots
                dj[t] = __shfl(d, j + q + 4 * t, 64);   // 0 for dead slots -> hot row 0
            }
            uint4 p[4];
#pragma unroll
            for (int t = 0; t < 4; ++t)
                p[t] = *(const uint4*)(hl + ((size_t)dj[t] << 7));
#pragma unroll
            for (int t = 0; t < 4; ++t) {
                float sv = sj[t];
                accA.x += sv * bflo(p[t].x); accA.y += sv * bfhi(p[t].x);
                accA.z += sv * bflo(p[t].y); accA.w += sv * bfhi(p[t].y);
                accB.x += sv * bflo(p[t].z); accB.y += sv * bfhi(p[t].z);
                accB.z += sv * bflo(p[t].w); accB.w += sv * bfhi(p[t].w);
                dn += sv;
            }
        }
    }

    float vals[9] = {accA.x, accA.y, accA.z, accA.w,
                     accB.x, accB.y, accB.z, accB.w, dn};
#pragma unroll
    for (int m = 32; m >= 16; m >>= 1)
#pragma unroll
        for (int i = 0; i < 9; ++i) vals[i] += __shfl_xor(vals[i], m, 64);

    if (q == 0) {
        float inv = (end > start) ? 1.f / vals[8] : 0.f;
        f32x4 o0 = {vals[0] * inv, vals[1] * inv, vals[2] * inv, vals[3] * inv};
        f32x4 o1 = {vals[4] * inv, vals[5] * inv, vals[6] * inv, vals[7] * inv};
        float* op = out + (size_t)node * D + l16 * 8;
        __builtin_nontemporal_store(o0, (f32x4*)op);       // out never re-read: keep L2 for h
        __builtin_nontemporal_store(o1, (f32x4*)(op + 4));
    }
}

extern "C" void kernel_launch(void* const* d_in, const int* in_sizes, int n_in,
                              void* d_out, int out_size, void* d_ws, size_t ws_size,
                              hipStream_t stream) {
    const float* X     = (const float*)d_in[0];   // 50000 x 128
    const int*   edges = (const int*)d_in[1];     // 800000 x 2 (src,dst), src sorted
    const float* W     = (const float*)d_in[2];   // 128 x 128
    const float* ka    = (const float*)d_in[3];   // 256 x 1

    char* ws = (char*)d_ws;
    unsigned short* h  = (unsigned short*)ws;                       // 12.8 MB bf16
    float* a_src   = (float*)(ws + (size_t)N_NODES * D * 2);        // 200 KB
    float* a_dst   = a_src + N_NODES;                               // 200 KB
    int*   row_ptr = (int*)(a_dst + N_NODES);                       // 50001 ints
    float* out = (float*)d_out;

    kh_fused<<<SEARCH_BLOCKS + GEMM_BLOCKS, 256, 0, stream>>>(
        X, edges, W, ka, h, a_src, a_dst, row_ptr);
    k3<<<(N_NODES + 3) / 4, 256, 0, stream>>>(edges, row_ptr, h, a_src, a_dst, out);
}